// Round 3
// baseline (102432.373 us; speedup 1.0000x reference)
//
#include <hip/hip_runtime.h>
#include <float.h>

#define VOCAB 50257
#define EMBED 512
#define HIDDEN 1024
#define SEQLEN 512
#define XDIM 1024  // 2*EMBED
#define CAND_CAP 2048
#define LB_PAD 50304  // VOCAB padded to /16

typedef unsigned long long u64;
typedef unsigned int u32;
typedef unsigned short u16;

// monotone mapping float -> u32 (order-preserving for all finite floats)
__device__ __forceinline__ u32 fmono(float f) {
  u32 b = __float_as_uint(f);
  return b ^ ((b & 0x80000000u) ? 0xFFFFFFFFu : 0x80000000u);
}

__device__ __forceinline__ float wave_reduce_sum(float v) {
#pragma unroll
  for (int off = 32; off > 0; off >>= 1) v += __shfl_down(v, off);
  return v;
}

__device__ __forceinline__ u64 wave_reduce_max_u64(u64 v) {
#pragma unroll
  for (int off = 32; off > 0; off >>= 1) {
    u64 o = __shfl_down(v, off);
    if (o > v) v = o;
  }
  return v;
}

// fp32 -> bf16 round-to-nearest-even (finite inputs only)
__device__ __forceinline__ u16 f2bf_rne(float f) {
  u32 u = __float_as_uint(f);
  u32 r = (u + 0x7FFFu + ((u >> 16) & 1u)) >> 16;
  return (u16)r;
}

// dot of 8 bf16 (packed in uint4) with 8 fp32 (two float4)
__device__ __forceinline__ float dot8(uint4 w, float4 hx, float4 hy) {
  float a = 0.f;
  u32 u;
  u = w.x; a += __uint_as_float(u << 16) * hx.x + __uint_as_float(u & 0xFFFF0000u) * hx.y;
  u = w.y; a += __uint_as_float(u << 16) * hx.z + __uint_as_float(u & 0xFFFF0000u) * hx.w;
  u = w.z; a += __uint_as_float(u << 16) * hy.x + __uint_as_float(u & 0xFFFF0000u) * hy.y;
  u = w.w; a += __uint_as_float(u << 16) * hy.z + __uint_as_float(u & 0xFFFF0000u) * hy.w;
  return a;
}

// ============================ setup kernels ============================

__global__ void init_state(const float* __restrict__ h0, const float* __restrict__ c0,
                           float* __restrict__ hbufs, float* __restrict__ cbufs,
                           float* __restrict__ xprev, float* __restrict__ Lb,
                           u64* __restrict__ gmax, u32* __restrict__ done) {
  int i = threadIdx.x;
  if (i < HIDDEN) {
    hbufs[i] = h0[i];
    cbufs[i] = c0[i];
  }
  if (i < EMBED) xprev[i] = 0.0f;
  if (i < LB_PAD - VOCAB) Lb[VOCAB + i] = -FLT_MAX;  // pad tail
  if (i == 0) {
    *gmax = 0ull;
    *done = 0u;
  }
}

// one-shot fp32 -> bf16 conversion of W_lin into workspace
__global__ __launch_bounds__(256)
void convert_wlin(const float* __restrict__ wlin, u16* __restrict__ wb) {
  const long long i8 = (long long)blockIdx.x * 256 + threadIdx.x;  // group of 8 floats
  const long long n8 = (long long)VOCAB * HIDDEN / 8;
  if (i8 >= n8) return;
  const float4* src = (const float4*)wlin;
  float4 a = src[2 * i8];
  float4 b = src[2 * i8 + 1];
  uint4 o;
  o.x = (u32)f2bf_rne(a.x) | ((u32)f2bf_rne(a.y) << 16);
  o.y = (u32)f2bf_rne(a.z) | ((u32)f2bf_rne(a.w) << 16);
  o.z = (u32)f2bf_rne(b.x) | ((u32)f2bf_rne(b.y) << 16);
  o.w = (u32)f2bf_rne(b.z) | ((u32)f2bf_rne(b.w) << 16);
  ((uint4*)wb)[i8] = o;
}

// ============================ fast path ============================

// LSTM step. 256 blocks x 256 threads; each wave owns one hidden unit j.
// prev-token embedding comes pre-gathered in xprev (written by the screen's
// last-block refine, or zeros from init at t=0). No argmax logic here.
__global__ __launch_bounds__(256)
void lstm_step(const float* __restrict__ emb,
               const float* __restrict__ wih, const float* __restrict__ whh,
               const float* __restrict__ bih, const float* __restrict__ bhh,
               const int* __restrict__ seq, const float* __restrict__ xprev,
               float* __restrict__ hbufs, float* __restrict__ cbufs, int t) {
  __shared__ __align__(16) float xs[XDIM];
  __shared__ __align__(16) float hs[HIDDEN];

  const int tid = threadIdx.x;
  const int lane = tid & 63;
  const int wid = tid >> 6;

  const float* hin = hbufs + (t & 1) * HIDDEN;
  const float* cin = cbufs + (t & 1) * HIDDEN;
  float* hout = hbufs + ((t + 1) & 1) * HIDDEN;
  float* cout = cbufs + ((t + 1) & 1) * HIDDEN;

  const int tok = seq[t];
  for (int i = tid; i < EMBED; i += 256) {
    xs[i] = xprev[i];
    xs[EMBED + i] = emb[(size_t)tok * EMBED + i];
  }
  for (int i = tid; i < HIDDEN; i += 256) hs[i] = hin[i];
  __syncthreads();

  // gates: each wave computes rows {j, j+H, j+2H, j+3H}
  const int j = blockIdx.x * 4 + wid;
  float acc[4];
#pragma unroll
  for (int g = 0; g < 4; ++g) {
    const float4* wx = (const float4*)(wih + (size_t)(g * HIDDEN + j) * XDIM);
    const float4* wh = (const float4*)(whh + (size_t)(g * HIDDEN + j) * HIDDEN);
    float a = 0.f;
#pragma unroll
    for (int i = 0; i < 4; ++i) {
      const int k = lane + i * 64;
      float4 w4 = wx[k];
      float4 x4 = *((const float4*)&xs[k * 4]);
      a += w4.x * x4.x + w4.y * x4.y + w4.z * x4.z + w4.w * x4.w;
      float4 v4 = wh[k];
      float4 h4 = *((const float4*)&hs[k * 4]);
      a += v4.x * h4.x + v4.y * h4.y + v4.z * h4.z + v4.w * h4.w;
    }
    acc[g] = wave_reduce_sum(a);
  }

  if (lane == 0) {
    float gi = acc[0] + bih[j] + bhh[j];
    float gf = acc[1] + bih[HIDDEN + j] + bhh[HIDDEN + j];
    float gg = acc[2] + bih[2 * HIDDEN + j] + bhh[2 * HIDDEN + j];
    float go = acc[3] + bih[3 * HIDDEN + j] + bhh[3 * HIDDEN + j];
    float si = 1.0f / (1.0f + expf(-gi));
    float sf = 1.0f / (1.0f + expf(-gf));
    float tg = tanhf(gg);
    float so = 1.0f / (1.0f + expf(-go));
    float c2 = sf * cin[j] + si * tg;
    float h2 = so * tanhf(c2);
    cout[j] = c2;
    hout[j] = h2;
  }
}

// bf16 screen: Lb = W_bf16 @ h + b for all rows; one global packed-max slot.
// The LAST block to finish (threadfence + done-counter) performs the exact
// argmax refine: threshold from the rigorous bf16 error bound, vectorized Lb
// scan, exact fp32 recompute of candidates (round-0 dot order), writes
// xprev = emb[argmax], resets gmax/done for the next step.
__global__ __launch_bounds__(256)
void logits_screen(const u16* __restrict__ wb, const float* __restrict__ blin,
                   const float* __restrict__ wlin, const float* __restrict__ emb,
                   const float* __restrict__ hbufs, float* __restrict__ Lb,
                   u64* __restrict__ gmax, u32* __restrict__ done,
                   float* __restrict__ xprev, int t) {
  __shared__ __align__(16) float hsh[HIDDEN];
  __shared__ int amLastS;

  const int tid = threadIdx.x;
  const int lane = tid & 63;
  const int wid = tid >> 6;

  const float* h = hbufs + ((t + 1) & 1) * HIDDEN;
  for (int i = tid; i < HIDDEN; i += 256) hsh[i] = h[i];

  // h fragments in registers (no LDS bank conflicts in the hot loop)
  const float4* h4p = (const float4*)h;
  const float4 ha0 = h4p[2 * lane];
  const float4 ha1 = h4p[2 * lane + 1];
  const float4 hb0 = h4p[2 * (lane + 64)];
  const float4 hb1 = h4p[2 * (lane + 64) + 1];

  const int row0 = blockIdx.x * 32 + wid * 8;
  float acc[8];
  uint4 w0[4], w1[4];
  const uint4 z4 = make_uint4(0u, 0u, 0u, 0u);

  // group 0: rows 0..3 — stage all loads, then compute (ILP)
#pragma unroll
  for (int r = 0; r < 4; ++r) {
    const int row = row0 + r;
    const uint4* wr = (const uint4*)(wb + (size_t)row * HIDDEN);
    const bool ok = row < VOCAB;
    w0[r] = ok ? wr[lane] : z4;
    w1[r] = ok ? wr[lane + 64] : z4;
  }
#pragma unroll
  for (int r = 0; r < 4; ++r)
    acc[r] = dot8(w0[r], ha0, ha1) + dot8(w1[r], hb0, hb1);

  // group 1: rows 4..7
#pragma unroll
  for (int r = 0; r < 4; ++r) {
    const int row = row0 + 4 + r;
    const uint4* wr = (const uint4*)(wb + (size_t)row * HIDDEN);
    const bool ok = row < VOCAB;
    w0[r] = ok ? wr[lane] : z4;
    w1[r] = ok ? wr[lane + 64] : z4;
  }
#pragma unroll
  for (int r = 0; r < 4; ++r)
    acc[4 + r] = dot8(w0[r], ha0, ha1) + dot8(w1[r], hb0, hb1);

  // 8 interleaved reduce chains
#pragma unroll
  for (int off = 32; off > 0; off >>= 1) {
#pragma unroll
    for (int r = 0; r < 8; ++r) acc[r] += __shfl_down(acc[r], off);
  }

  if (lane == 0) {
    u64 best = 0;
#pragma unroll
    for (int r = 0; r < 8; ++r) {
      const int row = row0 + r;
      if (row < VOCAB) {
        const float lg = acc[r] + blin[row];
        Lb[row] = lg;
        const u64 pk = ((u64)fmono(lg) << 32) | (u32)(VOCAB - row);
        if (pk > best) best = pk;
      }
    }
    if (best) atomicMax(gmax, best);
  }

  // ---- last-block detection ----
  __threadfence();   // release this thread's Lb stores (device scope)
  __syncthreads();
  if (tid == 0) amLastS = (atomicAdd(done, 1u) == (u32)(gridDim.x - 1)) ? 1 : 0;
  __syncthreads();
  if (!amLastS) return;
  __threadfence();   // acquire: all blocks' Lb stores + gmax now visible

  // ---- exact argmax refine (one block) ----
  __shared__ float sred[4];
  __shared__ u64 bred[4];
  __shared__ int list[CAND_CAP];
  __shared__ int cnt;
  __shared__ int ptokS;

  float s = 0.f;
  for (int i = tid; i < HIDDEN; i += 256) s += fabsf(hsh[i]);
  s = wave_reduce_sum(s);
  if (lane == 0) sred[wid] = s;
  if (tid == 0) cnt = 0;
  __syncthreads();

  const float S = sred[0] + sred[1] + sred[2] + sred[3];
  const u64 m = *(volatile u64*)gmax;
  const int mrow = VOCAB - (int)(u32)(m & 0xFFFFFFFFu);
  const float maxb = Lb[mrow];
  // |logit_bf16 - logit_fp32| <= S*(1/32)*2^-8 each side, + fp32 order margin
  const float thr = maxb - 2.0f * (S * 1.220703125e-4f) - 2e-3f;

  const float4* Lb4 = (const float4*)Lb;
  for (int i4 = tid; i4 < LB_PAD / 4; i4 += 256) {
    const float4 L = Lb4[i4];
    const int r0 = i4 << 2;
    if (L.x >= thr) { int ix = atomicAdd(&cnt, 1); if (ix < CAND_CAP) list[ix] = r0; }
    if (L.y >= thr) { int ix = atomicAdd(&cnt, 1); if (ix < CAND_CAP) list[ix] = r0 + 1; }
    if (L.z >= thr) { int ix = atomicAdd(&cnt, 1); if (ix < CAND_CAP) list[ix] = r0 + 2; }
    if (L.w >= thr) { int ix = atomicAdd(&cnt, 1); if (ix < CAND_CAP) list[ix] = r0 + 3; }
  }
  __syncthreads();
  const int nc = (cnt < CAND_CAP) ? cnt : CAND_CAP;

  u64 best2 = 0;
  for (int ci = wid; ci < nc; ci += 4) {
    const int row = list[ci];
    const float4* wr = (const float4*)(wlin + (size_t)row * HIDDEN);
    float a = 0.f;
#pragma unroll
    for (int i = 0; i < 4; ++i) {
      const int k = lane + i * 64;
      const float4 w4 = wr[k];
      const float4 h4 = *((const float4*)&hsh[k * 4]);
      a += w4.x * h4.x + w4.y * h4.y + w4.z * h4.z + w4.w * h4.w;
    }
    a = wave_reduce_sum(a);
    if (lane == 0) {
      const u64 pk = ((u64)fmono(a + blin[row]) << 32) | (u32)(VOCAB - row);
      if (pk > best2) best2 = pk;
    }
  }
  if (lane == 0) bred[wid] = best2;
  __syncthreads();
  if (tid == 0) {
    u64 b = bred[0];
    if (bred[1] > b) b = bred[1];
    if (bred[2] > b) b = bred[2];
    if (bred[3] > b) b = bred[3];
    ptokS = VOCAB - (int)(u32)(b & 0xFFFFFFFFu);
    *(volatile u64*)gmax = 0ull;  // reset for next step
    *(volatile u32*)done = 0u;
  }
  __syncthreads();
  const int pt = ptokS;
  for (int i = tid; i < EMBED; i += 256) xprev[i] = emb[(size_t)pt * EMBED + i];
}

// exact fp32 logits of the final step -> d_out (identical dot to round 0)
__global__ __launch_bounds__(256)
void logits_out(const float* __restrict__ wlin, const float* __restrict__ blin,
                const float* __restrict__ h, float* __restrict__ out) {
  __shared__ __align__(16) float hs[HIDDEN];
  const int tid = threadIdx.x;
  const int lane = tid & 63;
  const int wid = tid >> 6;
  for (int i = tid; i < HIDDEN; i += 256) hs[i] = h[i];
  __syncthreads();
  const int row = blockIdx.x * 4 + wid;
  if (row < VOCAB) {
    const float4* wr = (const float4*)(wlin + (size_t)row * HIDDEN);
    float a = 0.f;
#pragma unroll
    for (int i = 0; i < 4; ++i) {
      const int k = lane + i * 64;
      float4 w4 = wr[k];
      float4 h4 = *((const float4*)&hs[k * 4]);
      a += w4.x * h4.x + w4.y * h4.y + w4.z * h4.z + w4.w * h4.w;
    }
    a = wave_reduce_sum(a);
    if (lane == 0) out[row] = a + blin[row];
  }
}

// ====================== fallback (round-0) path ======================

__global__ void init_state_v0(const float* __restrict__ h0, const float* __restrict__ c0,
                              float* __restrict__ hbufs, float* __restrict__ cbufs,
                              u64* __restrict__ partials) {
  int i = threadIdx.x;
  if (i < HIDDEN) {
    hbufs[i] = h0[i];
    cbufs[i] = c0[i];
  }
  if (i < 512) partials[i] = 0ull;
}

__global__ __launch_bounds__(256)
void lstm_step_v0(const float* __restrict__ emb,
                  const float* __restrict__ wih, const float* __restrict__ whh,
                  const float* __restrict__ bih, const float* __restrict__ bhh,
                  const int* __restrict__ seq,
                  float* __restrict__ hbufs, float* __restrict__ cbufs,
                  u64* __restrict__ partials, int t) {
  __shared__ __align__(16) float xs[XDIM];
  __shared__ __align__(16) float hs[HIDDEN];
  __shared__ u64 red[4];
  __shared__ int ptok_s;

  const int tid = threadIdx.x;
  const int lane = tid & 63;
  const int wid = tid >> 6;

  const float* hin = hbufs + (t & 1) * HIDDEN;
  const float* cin = cbufs + (t & 1) * HIDDEN;
  float* hout = hbufs + ((t + 1) & 1) * HIDDEN;
  float* cout = cbufs + ((t + 1) & 1) * HIDDEN;

  int ptok = -1;
  if (t > 0) {
    const u64* part = partials + ((t + 1) & 1) * 256;
    u64 v = wave_reduce_max_u64(part[tid]);
    if (lane == 0) red[wid] = v;
    __syncthreads();
    if (tid == 0) {
      u64 m = red[0];
      if (red[1] > m) m = red[1];
      if (red[2] > m) m = red[2];
      if (red[3] > m) m = red[3];
      ptok_s = VOCAB - (int)(u32)(m & 0xFFFFFFFFu);
    }
    __syncthreads();
    ptok = ptok_s;
  }
  if (blockIdx.x == 0) partials[(t & 1) * 256 + tid] = 0ull;

  const int tok = seq[t];
  for (int i = tid; i < EMBED; i += 256) {
    xs[i] = (t == 0) ? 0.0f : emb[(size_t)ptok * EMBED + i];
    xs[EMBED + i] = emb[(size_t)tok * EMBED + i];
  }
  for (int i = tid; i < HIDDEN; i += 256) hs[i] = hin[i];
  __syncthreads();

  const int j = blockIdx.x * 4 + wid;
  float acc[4];
#pragma unroll
  for (int g = 0; g < 4; ++g) {
    const float4* wx = (const float4*)(wih + (size_t)(g * HIDDEN + j) * XDIM);
    const float4* wh = (const float4*)(whh + (size_t)(g * HIDDEN + j) * HIDDEN);
    float a = 0.f;
#pragma unroll
    for (int i = 0; i < 4; ++i) {
      const int k = lane + i * 64;
      float4 w4 = wx[k];
      float4 x4 = *((const float4*)&xs[k * 4]);
      a += w4.x * x4.x + w4.y * x4.y + w4.z * x4.z + w4.w * x4.w;
      float4 v4 = wh[k];
      float4 h4 = *((const float4*)&hs[k * 4]);
      a += v4.x * h4.x + v4.y * h4.y + v4.z * h4.z + v4.w * h4.w;
    }
    acc[g] = wave_reduce_sum(a);
  }

  if (lane == 0) {
    float gi = acc[0] + bih[j] + bhh[j];
    float gf = acc[1] + bih[HIDDEN + j] + bhh[HIDDEN + j];
    float gg = acc[2] + bih[2 * HIDDEN + j] + bhh[2 * HIDDEN + j];
    float go = acc[3] + bih[3 * HIDDEN + j] + bhh[3 * HIDDEN + j];
    float si = 1.0f / (1.0f + expf(-gi));
    float sf = 1.0f / (1.0f + expf(-gf));
    float tg = tanhf(gg);
    float so = 1.0f / (1.0f + expf(-go));
    float c2 = sf * cin[j] + si * tg;
    float h2 = so * tanhf(c2);
    cout[j] = c2;
    hout[j] = h2;
  }
}

__global__ __launch_bounds__(256)
void logits_step_v0(const float* __restrict__ wlin, const float* __restrict__ blin,
                    const float* __restrict__ hbufs, float* __restrict__ out,
                    u64* __restrict__ partials, int t) {
  __shared__ __align__(16) float hs[HIDDEN];
  __shared__ u64 red[4];
  const int tid = threadIdx.x;
  const int lane = tid & 63;
  const int wid = tid >> 6;

  const float* h = hbufs + ((t + 1) & 1) * HIDDEN;
  for (int i = tid; i < HIDDEN; i += 256) hs[i] = h[i];
  __syncthreads();

  const int row = blockIdx.x * 4 + wid;
  u64 pk = 0ull;
  if (row < VOCAB) {
    const float4* wr = (const float4*)(wlin + (size_t)row * HIDDEN);
    float a = 0.f;
#pragma unroll
    for (int i = 0; i < 4; ++i) {
      const int k = lane + i * 64;
      float4 w4 = wr[k];
      float4 h4 = *((const float4*)&hs[k * 4]);
      a += w4.x * h4.x + w4.y * h4.y + w4.z * h4.z + w4.w * h4.w;
    }
    a = wave_reduce_sum(a);
    if (lane == 0) {
      float logit = a + blin[row];
      out[row] = logit;
      pk = ((u64)fmono(logit) << 32) | (u32)(VOCAB - row);
    }
  }
  if (lane == 0) red[wid] = pk;
  __syncthreads();
  if (tid == 0) {
    u64 m = red[0];
    if (red[1] > m) m = red[1];
    if (red[2] > m) m = red[2];
    if (red[3] > m) m = red[3];
    atomicMax(&partials[(t & 1) * 256 + (blockIdx.x & 255)], m);
  }
}

extern "C" void kernel_launch(void* const* d_in, const int* in_sizes, int n_in,
                              void* d_out, int out_size, void* d_ws, size_t ws_size,
                              hipStream_t stream) {
  const int* seq = (const int*)d_in[0];
  const float* h0 = (const float*)d_in[1];
  const float* c0 = (const float*)d_in[2];
  const float* emb = (const float*)d_in[3];
  const float* wih = (const float*)d_in[4];
  const float* whh = (const float*)d_in[5];
  const float* bih = (const float*)d_in[6];
  const float* bhh = (const float*)d_in[7];
  const float* wlin = (const float*)d_in[8];
  const float* blin = (const float*)d_in[9];
  float* out = (float*)d_out;

  // ws layout (256B-aligned offsets)
  const size_t OFF_CTL = 0;                        // gmax (u64) + done (u32)
  const size_t OFF_H = 256;                        // hbufs: 2*1024 f
  const size_t OFF_C = OFF_H + 8192;               // cbufs: 2*1024 f
  const size_t OFF_X = OFF_C + 8192;               // xprev: 512 f
  const size_t OFF_LB = OFF_X + 2048;              // Lb: LB_PAD f
  const size_t OFF_WB = OFF_LB + LB_PAD * 4;       // wb: VOCAB*HIDDEN bf16
  const size_t NEED = OFF_WB + (size_t)VOCAB * HIDDEN * 2;

  u64* gmax = (u64*)((char*)d_ws + OFF_CTL);
  u32* done = (u32*)((char*)d_ws + OFF_CTL + 8);
  float* hbufs = (float*)((char*)d_ws + OFF_H);
  float* cbufs = (float*)((char*)d_ws + OFF_C);
  float* xprev = (float*)((char*)d_ws + OFF_X);
  float* Lb = (float*)((char*)d_ws + OFF_LB);
  u16* wb = (u16*)((char*)d_ws + OFF_WB);

  if (ws_size >= NEED) {
    init_state<<<1, 1024, 0, stream>>>(h0, c0, hbufs, cbufs, xprev, Lb, gmax, done);
    const long long n8 = (long long)VOCAB * HIDDEN / 8;
    convert_wlin<<<(int)((n8 + 255) / 256), 256, 0, stream>>>(wlin, wb);
    const int nscreen = (VOCAB + 31) / 32;
    for (int t = 0; t < SEQLEN; ++t) {
      lstm_step<<<HIDDEN / 4, 256, 0, stream>>>(emb, wih, whh, bih, bhh, seq,
                                                xprev, hbufs, cbufs, t);
      if (t < SEQLEN - 1)
        logits_screen<<<nscreen, 256, 0, stream>>>(wb, blin, wlin, emb, hbufs,
                                                   Lb, gmax, done, xprev, t);
    }
    // final h lives at parity (511+1)&1 == 0
    logits_out<<<(VOCAB + 3) / 4, 256, 0, stream>>>(wlin, blin, hbufs, out);
  } else {
    // fallback: round-0 fp32 path
    u64* partials = (u64*)d_ws;
    float* hb0 = (float*)((char*)d_ws + 4096);
    float* cb0 = hb0 + 2 * HIDDEN;
    init_state_v0<<<1, 1024, 0, stream>>>(h0, c0, hb0, cb0, partials);
    for (int t = 0; t < SEQLEN; ++t) {
      lstm_step_v0<<<HIDDEN / 4, 256, 0, stream>>>(emb, wih, whh, bih, bhh, seq,
                                                   hb0, cb0, partials, t);
      logits_step_v0<<<(VOCAB + 3) / 4, 256, 0, stream>>>(wlin, blin, hb0, out,
                                                          partials, t);
    }
  }
}

// Round 4
// 23121.347 us; speedup vs baseline: 4.4302x; 4.4302x over previous
//
#include <hip/hip_runtime.h>

#define VOCAB 50257
#define EMBED 512
#define HIDDEN 1024
#define SEQLEN 512
#define XDIM 1024   // 2*EMBED
#define NSB 1571    // ceil(VOCAB/32): screen blocks / per-block max slots
#define CANDB 128   // candidate-block cap
#define CANDR 512   // candidate-row cap

typedef unsigned long long u64;
typedef unsigned int u32;
typedef unsigned short u16;

// monotone mapping float -> u32 (order-preserving for all finite floats)
__device__ __forceinline__ u32 fmono(float f) {
  u32 b = __float_as_uint(f);
  return b ^ ((b & 0x80000000u) ? 0xFFFFFFFFu : 0x80000000u);
}
// inverse of fmono
__device__ __forceinline__ float funmono(u32 v) {
  u32 b = (v & 0x80000000u) ? (v ^ 0x80000000u) : ~v;
  return __uint_as_float(b);
}

__device__ __forceinline__ float wave_reduce_sum(float v) {
#pragma unroll
  for (int off = 32; off > 0; off >>= 1) v += __shfl_down(v, off);
  return v;
}

__device__ __forceinline__ u64 wave_reduce_max_u64(u64 v) {
#pragma unroll
  for (int off = 32; off > 0; off >>= 1) {
    u64 o = __shfl_down(v, off);
    if (o > v) v = o;
  }
  return v;
}

// fp32 -> bf16 round-to-nearest-even (finite inputs only)
__device__ __forceinline__ u16 f2bf_rne(float f) {
  u32 u = __float_as_uint(f);
  u32 r = (u + 0x7FFFu + ((u >> 16) & 1u)) >> 16;
  return (u16)r;
}

// dot of 8 bf16 (packed in uint4) with 8 fp32 (two float4)
__device__ __forceinline__ float dot8(uint4 w, float4 hx, float4 hy) {
  float a = 0.f;
  u32 u;
  u = w.x; a += __uint_as_float(u << 16) * hx.x + __uint_as_float(u & 0xFFFF0000u) * hx.y;
  u = w.y; a += __uint_as_float(u << 16) * hx.z + __uint_as_float(u & 0xFFFF0000u) * hx.w;
  u = w.z; a += __uint_as_float(u << 16) * hy.x + __uint_as_float(u & 0xFFFF0000u) * hy.y;
  u = w.w; a += __uint_as_float(u << 16) * hy.z + __uint_as_float(u & 0xFFFF0000u) * hy.w;
  return a;
}

// ============================ setup kernels ============================

__global__ void init_state(const float* __restrict__ h0, const float* __restrict__ c0,
                           float* __restrict__ hbufs, float* __restrict__ cbufs) {
  int i = threadIdx.x;
  if (i < HIDDEN) {
    hbufs[i] = h0[i];
    cbufs[i] = c0[i];
  }
}

// one-shot fp32 -> bf16 conversion of W_lin into workspace
__global__ __launch_bounds__(256)
void convert_wlin(const float* __restrict__ wlin, u16* __restrict__ wb) {
  const long long i8 = (long long)blockIdx.x * 256 + threadIdx.x;  // group of 8 floats
  const long long n8 = (long long)VOCAB * HIDDEN / 8;
  if (i8 >= n8) return;
  const float4* src = (const float4*)wlin;
  float4 a = src[2 * i8];
  float4 b = src[2 * i8 + 1];
  uint4 o;
  o.x = (u32)f2bf_rne(a.x) | ((u32)f2bf_rne(a.y) << 16);
  o.y = (u32)f2bf_rne(a.z) | ((u32)f2bf_rne(a.w) << 16);
  o.z = (u32)f2bf_rne(b.x) | ((u32)f2bf_rne(b.y) << 16);
  o.w = (u32)f2bf_rne(b.z) | ((u32)f2bf_rne(b.w) << 16);
  ((uint4*)wb)[i8] = o;
}

// ============================ fast path ============================

// LSTM step, 256 blocks x 256 threads. Prologue (t>0, redundant per block,
// cheap): reduce NSB per-screen-block maxima -> global bf16 max; rigorous
// threshold; candidate BLOCKS (block-max >= thr); scan only their 32-row Lb
// segments; exact fp32 recompute of candidate rows (round-0 dot order) ->
// ptok. Then the LSTM gates. All cross-kernel visibility is via stream order
// (kernel boundary) — no fences, no global atomics.
__global__ __launch_bounds__(256)
void lstm_step(const float* __restrict__ emb,
               const float* __restrict__ wih, const float* __restrict__ whh,
               const float* __restrict__ bih, const float* __restrict__ bhh,
               const int* __restrict__ seq,
               const float* __restrict__ wlin, const float* __restrict__ blin,
               float* __restrict__ hbufs, float* __restrict__ cbufs,
               const u64* __restrict__ partials, const float* __restrict__ Lb,
               int t) {
  __shared__ __align__(16) float xs[XDIM];
  __shared__ __align__(16) float hs[HIDDEN];
  __shared__ float sred[4];
  __shared__ u64 mred[4];
  __shared__ u64 bred[4];
  __shared__ int listb[CANDB];
  __shared__ int listr[CANDR];
  __shared__ int cntb, cntr;
  __shared__ int ptokS;

  const int tid = threadIdx.x;
  const int lane = tid & 63;
  const int wid = tid >> 6;

  const float* hin = hbufs + (t & 1) * HIDDEN;
  const float* cin = cbufs + (t & 1) * HIDDEN;
  float* hout = hbufs + ((t + 1) & 1) * HIDDEN;
  float* cout = cbufs + ((t + 1) & 1) * HIDDEN;

  // stage h (each thread later sums |h| over exactly the elements it wrote)
  for (int i = tid; i < HIDDEN; i += 256) hs[i] = hin[i];

  int ptok = 0;
  if (t > 0) {
    const u64* part = partials + ((t + 1) & 1) * NSB;  // parity (t-1)&1
    // pass 1: load per-screen-block maxima, keep in registers, fold max
    u64 pks[8];
    u64 v = 0;
    int np = 0;
    for (int i = tid; i < NSB; i += 256) {
      u64 p = part[i];
      pks[np++] = p;
      if (p > v) v = p;
    }
    v = wave_reduce_max_u64(v);
    float s = 0.f;
    for (int i = tid; i < HIDDEN; i += 256) s += fabsf(hs[i]);
    s = wave_reduce_sum(s);
    if (lane == 0) {
      mred[wid] = v;
      sred[wid] = s;
    }
    if (tid == 0) { cntb = 0; cntr = 0; }
    __syncthreads();

    u64 m = mred[0];
    if (mred[1] > m) m = mred[1];
    if (mred[2] > m) m = mred[2];
    if (mred[3] > m) m = mred[3];
    const float S = sred[0] + sred[1] + sred[2] + sred[3];
    const float maxb = funmono((u32)(m >> 32));
    // |logit_bf16 - logit_fp32| <= S*(1/32)*2^-9 per side; margins doubled
    const float thr = maxb - 2.0f * (S * 1.220703125e-4f) - 2e-3f;

    // pass 2: candidate blocks from registers
    int np2 = 0;
    for (int i = tid; i < NSB; i += 256) {
      u64 p = pks[np2++];
      if (funmono((u32)(p >> 32)) >= thr) {
        int ix = atomicAdd(&cntb, 1);
        if (ix < CANDB) listb[ix] = i;
      }
    }
    __syncthreads();
    const int nb = (cntb < CANDB) ? cntb : CANDB;

    // scan candidate blocks' Lb segments for candidate rows
    for (int idx = tid; idx < nb * 32; idx += 256) {
      const int row = listb[idx >> 5] * 32 + (idx & 31);
      if (row < VOCAB && Lb[row] >= thr) {
        int ix = atomicAdd(&cntr, 1);
        if (ix < CANDR) listr[ix] = row;
      }
    }
    __syncthreads();
    const int nr = (cntr < CANDR) ? cntr : CANDR;

    // exact fp32 recompute of candidate rows, one wave per row
    u64 best = 0;
    for (int ci = wid; ci < nr; ci += 4) {
      const int row = listr[ci];
      const float4* wr = (const float4*)(wlin + (size_t)row * HIDDEN);
      float a = 0.f;
#pragma unroll
      for (int i = 0; i < 4; ++i) {
        const int k = lane + i * 64;
        const float4 w4 = wr[k];
        const float4 h4 = *((const float4*)&hs[k * 4]);
        a += w4.x * h4.x + w4.y * h4.y + w4.z * h4.z + w4.w * h4.w;
      }
      a = wave_reduce_sum(a);
      if (lane == 0) {
        const u64 pk = ((u64)fmono(a + blin[row]) << 32) | (u32)(VOCAB - row);
        if (pk > best) best = pk;
      }
    }
    if (lane == 0) bred[wid] = best;
    __syncthreads();
    if (tid == 0) {
      u64 b = bred[0];
      if (bred[1] > b) b = bred[1];
      if (bred[2] > b) b = bred[2];
      if (bred[3] > b) b = bred[3];
      ptokS = VOCAB - (int)(u32)(b & 0xFFFFFFFFu);
    }
    __syncthreads();
    ptok = ptokS;
  }

  // stage x = [prev_embed, tok_embed]
  const int tok = seq[t];
  for (int i = tid; i < EMBED; i += 256) {
    xs[i] = (t == 0) ? 0.0f : emb[(size_t)ptok * EMBED + i];
    xs[EMBED + i] = emb[(size_t)tok * EMBED + i];
  }
  __syncthreads();  // covers hs writes too (t==0 path)

  // gates: each wave computes rows {j, j+H, j+2H, j+3H}
  const int j = blockIdx.x * 4 + wid;
  float acc[4];
#pragma unroll
  for (int g = 0; g < 4; ++g) {
    const float4* wx = (const float4*)(wih + (size_t)(g * HIDDEN + j) * XDIM);
    const float4* wh = (const float4*)(whh + (size_t)(g * HIDDEN + j) * HIDDEN);
    float a = 0.f;
#pragma unroll
    for (int i = 0; i < 4; ++i) {
      const int k = lane + i * 64;
      float4 w4 = wx[k];
      float4 x4 = *((const float4*)&xs[k * 4]);
      a += w4.x * x4.x + w4.y * x4.y + w4.z * x4.z + w4.w * x4.w;
      float4 v4 = wh[k];
      float4 h4 = *((const float4*)&hs[k * 4]);
      a += v4.x * h4.x + v4.y * h4.y + v4.z * h4.z + v4.w * h4.w;
    }
    acc[g] = wave_reduce_sum(a);
  }

  if (lane == 0) {
    float gi = acc[0] + bih[j] + bhh[j];
    float gf = acc[1] + bih[HIDDEN + j] + bhh[HIDDEN + j];
    float gg = acc[2] + bih[2 * HIDDEN + j] + bhh[2 * HIDDEN + j];
    float go = acc[3] + bih[3 * HIDDEN + j] + bhh[3 * HIDDEN + j];
    float si = 1.0f / (1.0f + expf(-gi));
    float sf = 1.0f / (1.0f + expf(-gf));
    float tg = tanhf(gg);
    float so = 1.0f / (1.0f + expf(-go));
    float c2 = sf * cin[j] + si * tg;
    float h2 = so * tanhf(c2);
    cout[j] = c2;
    hout[j] = h2;
  }
}

// bf16 screen: Lb = W_bf16 @ h + b for its 32 rows; per-block packed max
// written to the block's OWN slot (plain store — no atomics, no fences).
__global__ __launch_bounds__(256)
void logits_screen(const u16* __restrict__ wb, const float* __restrict__ blin,
                   const float* __restrict__ hbufs, float* __restrict__ Lb,
                   u64* __restrict__ partials, int t) {
  __shared__ u64 red[4];
  const int tid = threadIdx.x;
  const int lane = tid & 63;
  const int wid = tid >> 6;

  const float* h = hbufs + ((t + 1) & 1) * HIDDEN;

  // h fragments in registers (no LDS bank conflicts in the hot loop)
  const float4* h4p = (const float4*)h;
  const float4 ha0 = h4p[2 * lane];
  const float4 ha1 = h4p[2 * lane + 1];
  const float4 hb0 = h4p[2 * (lane + 64)];
  const float4 hb1 = h4p[2 * (lane + 64) + 1];

  const int row0 = blockIdx.x * 32 + wid * 8;
  float acc[8];
  uint4 w0[4], w1[4];
  const uint4 z4 = make_uint4(0u, 0u, 0u, 0u);

  // group 0: rows 0..3 — stage all loads, then compute (ILP)
#pragma unroll
  for (int r = 0; r < 4; ++r) {
    const int row = row0 + r;
    const uint4* wr = (const uint4*)(wb + (size_t)row * HIDDEN);
    const bool ok = row < VOCAB;
    w0[r] = ok ? wr[lane] : z4;
    w1[r] = ok ? wr[lane + 64] : z4;
  }
#pragma unroll
  for (int r = 0; r < 4; ++r)
    acc[r] = dot8(w0[r], ha0, ha1) + dot8(w1[r], hb0, hb1);

  // group 1: rows 4..7
#pragma unroll
  for (int r = 0; r < 4; ++r) {
    const int row = row0 + 4 + r;
    const uint4* wr = (const uint4*)(wb + (size_t)row * HIDDEN);
    const bool ok = row < VOCAB;
    w0[r] = ok ? wr[lane] : z4;
    w1[r] = ok ? wr[lane + 64] : z4;
  }
#pragma unroll
  for (int r = 0; r < 4; ++r)
    acc[4 + r] = dot8(w0[r], ha0, ha1) + dot8(w1[r], hb0, hb1);

  // 8 interleaved reduce chains
#pragma unroll
  for (int off = 32; off > 0; off >>= 1) {
#pragma unroll
    for (int r = 0; r < 8; ++r) acc[r] += __shfl_down(acc[r], off);
  }

  u64 best = 0;
  if (lane == 0) {
#pragma unroll
    for (int r = 0; r < 8; ++r) {
      const int row = row0 + r;
      if (row < VOCAB) {
        const float lg = acc[r] + blin[row];
        Lb[row] = lg;
        const u64 pk = ((u64)fmono(lg) << 32) | (u32)(VOCAB - row);
        if (pk > best) best = pk;
      }
    }
    red[wid] = best;
  }
  __syncthreads();
  if (tid == 0) {
    u64 m = red[0];
    if (red[1] > m) m = red[1];
    if (red[2] > m) m = red[2];
    if (red[3] > m) m = red[3];
    partials[(t & 1) * NSB + blockIdx.x] = m;  // own slot, plain store
  }
}

// exact fp32 logits of the final step -> d_out (identical dot to round 0)
__global__ __launch_bounds__(256)
void logits_out(const float* __restrict__ wlin, const float* __restrict__ blin,
                const float* __restrict__ h, float* __restrict__ out) {
  __shared__ __align__(16) float hs[HIDDEN];
  const int tid = threadIdx.x;
  const int lane = tid & 63;
  const int wid = tid >> 6;
  for (int i = tid; i < HIDDEN; i += 256) hs[i] = h[i];
  __syncthreads();
  const int row = blockIdx.x * 4 + wid;
  if (row < VOCAB) {
    const float4* wr = (const float4*)(wlin + (size_t)row * HIDDEN);
    float a = 0.f;
#pragma unroll
    for (int i = 0; i < 4; ++i) {
      const int k = lane + i * 64;
      float4 w4 = wr[k];
      float4 h4 = *((const float4*)&hs[k * 4]);
      a += w4.x * h4.x + w4.y * h4.y + w4.z * h4.z + w4.w * h4.w;
    }
    a = wave_reduce_sum(a);
    if (lane == 0) out[row] = a + blin[row];
  }
}

// ====================== fallback (round-0) path ======================

__global__ void init_state_v0(const float* __restrict__ h0, const float* __restrict__ c0,
                              float* __restrict__ hbufs, float* __restrict__ cbufs,
                              u64* __restrict__ partials) {
  int i = threadIdx.x;
  if (i < HIDDEN) {
    hbufs[i] = h0[i];
    cbufs[i] = c0[i];
  }
  if (i < 512) partials[i] = 0ull;
}

__global__ __launch_bounds__(256)
void lstm_step_v0(const float* __restrict__ emb,
                  const float* __restrict__ wih, const float* __restrict__ whh,
                  const float* __restrict__ bih, const float* __restrict__ bhh,
                  const int* __restrict__ seq,
                  float* __restrict__ hbufs, float* __restrict__ cbufs,
                  u64* __restrict__ partials, int t) {
  __shared__ __align__(16) float xs[XDIM];
  __shared__ __align__(16) float hs[HIDDEN];
  __shared__ u64 red[4];
  __shared__ int ptok_s;

  const int tid = threadIdx.x;
  const int lane = tid & 63;
  const int wid = tid >> 6;

  const float* hin = hbufs + (t & 1) * HIDDEN;
  const float* cin = cbufs + (t & 1) * HIDDEN;
  float* hout = hbufs + ((t + 1) & 1) * HIDDEN;
  float* cout = cbufs + ((t + 1) & 1) * HIDDEN;

  int ptok = -1;
  if (t > 0) {
    const u64* part = partials + ((t + 1) & 1) * 256;
    u64 v = wave_reduce_max_u64(part[tid]);
    if (lane == 0) red[wid] = v;
    __syncthreads();
    if (tid == 0) {
      u64 m = red[0];
      if (red[1] > m) m = red[1];
      if (red[2] > m) m = red[2];
      if (red[3] > m) m = red[3];
      ptok_s = VOCAB - (int)(u32)(m & 0xFFFFFFFFu);
    }
    __syncthreads();
    ptok = ptok_s;
  }
  if (blockIdx.x == 0) partials[(t & 1) * 256 + tid] = 0ull;

  const int tok = seq[t];
  for (int i = tid; i < EMBED; i += 256) {
    xs[i] = (t == 0) ? 0.0f : emb[(size_t)ptok * EMBED + i];
    xs[EMBED + i] = emb[(size_t)tok * EMBED + i];
  }
  for (int i = tid; i < HIDDEN; i += 256) hs[i] = hin[i];
  __syncthreads();

  const int j = blockIdx.x * 4 + wid;
  float acc[4];
#pragma unroll
  for (int g = 0; g < 4; ++g) {
    const float4* wx = (const float4*)(wih + (size_t)(g * HIDDEN + j) * XDIM);
    const float4* wh = (const float4*)(whh + (size_t)(g * HIDDEN + j) * HIDDEN);
    float a = 0.f;
#pragma unroll
    for (int i = 0; i < 4; ++i) {
      const int k = lane + i * 64;
      float4 w4 = wx[k];
      float4 x4 = *((const float4*)&xs[k * 4]);
      a += w4.x * x4.x + w4.y * x4.y + w4.z * x4.z + w4.w * x4.w;
      float4 v4 = wh[k];
      float4 h4 = *((const float4*)&hs[k * 4]);
      a += v4.x * h4.x + v4.y * h4.y + v4.z * h4.z + v4.w * h4.w;
    }
    acc[g] = wave_reduce_sum(a);
  }

  if (lane == 0) {
    float gi = acc[0] + bih[j] + bhh[j];
    float gf = acc[1] + bih[HIDDEN + j] + bhh[HIDDEN + j];
    float gg = acc[2] + bih[2 * HIDDEN + j] + bhh[2 * HIDDEN + j];
    float go = acc[3] + bih[3 * HIDDEN + j] + bhh[3 * HIDDEN + j];
    float si = 1.0f / (1.0f + expf(-gi));
    float sf = 1.0f / (1.0f + expf(-gf));
    float tg = tanhf(gg);
    float so = 1.0f / (1.0f + expf(-go));
    float c2 = sf * cin[j] + si * tg;
    float h2 = so * tanhf(c2);
    cout[j] = c2;
    hout[j] = h2;
  }
}

__global__ __launch_bounds__(256)
void logits_step_v0(const float* __restrict__ wlin, const float* __restrict__ blin,
                    const float* __restrict__ hbufs, float* __restrict__ out,
                    u64* __restrict__ partials, int t) {
  __shared__ __align__(16) float hs[HIDDEN];
  __shared__ u64 red[4];
  const int tid = threadIdx.x;
  const int lane = tid & 63;
  const int wid = tid >> 6;

  const float* h = hbufs + ((t + 1) & 1) * HIDDEN;
  for (int i = tid; i < HIDDEN; i += 256) hs[i] = h[i];
  __syncthreads();

  const int row = blockIdx.x * 4 + wid;
  u64 pk = 0ull;
  if (row < VOCAB) {
    const float4* wr = (const float4*)(wlin + (size_t)row * HIDDEN);
    float a = 0.f;
#pragma unroll
    for (int i = 0; i < 4; ++i) {
      const int k = lane + i * 64;
      float4 w4 = wr[k];
      float4 h4 = *((const float4*)&hs[k * 4]);
      a += w4.x * h4.x + w4.y * h4.y + w4.z * h4.z + w4.w * h4.w;
    }
    a = wave_reduce_sum(a);
    if (lane == 0) {
      float logit = a + blin[row];
      out[row] = logit;
      pk = ((u64)fmono(logit) << 32) | (u32)(VOCAB - row);
    }
  }
  if (lane == 0) red[wid] = pk;
  __syncthreads();
  if (tid == 0) {
    u64 m = red[0];
    if (red[1] > m) m = red[1];
    if (red[2] > m) m = red[2];
    if (red[3] > m) m = red[3];
    atomicMax(&partials[(t & 1) * 256 + (blockIdx.x & 255)], m);
  }
}

extern "C" void kernel_launch(void* const* d_in, const int* in_sizes, int n_in,
                              void* d_out, int out_size, void* d_ws, size_t ws_size,
                              hipStream_t stream) {
  const int* seq = (const int*)d_in[0];
  const float* h0 = (const float*)d_in[1];
  const float* c0 = (const float*)d_in[2];
  const float* emb = (const float*)d_in[3];
  const float* wih = (const float*)d_in[4];
  const float* whh = (const float*)d_in[5];
  const float* bih = (const float*)d_in[6];
  const float* bhh = (const float*)d_in[7];
  const float* wlin = (const float*)d_in[8];
  const float* blin = (const float*)d_in[9];
  float* out = (float*)d_out;

  // ws layout (aligned offsets)
  const size_t OFF_P = 0;                          // partials: 2*NSB u64
  const size_t OFF_H = 25600;                      // hbufs: 2*1024 f
  const size_t OFF_C = OFF_H + 8192;               // cbufs: 2*1024 f
  const size_t OFF_LB = OFF_C + 8192;              // Lb: VOCAB f (pad to 16)
  const size_t OFF_WB = OFF_LB + 201216;           // wb: VOCAB*HIDDEN bf16
  const size_t NEED = OFF_WB + (size_t)VOCAB * HIDDEN * 2;

  u64* partials = (u64*)((char*)d_ws + OFF_P);
  float* hbufs = (float*)((char*)d_ws + OFF_H);
  float* cbufs = (float*)((char*)d_ws + OFF_C);
  float* Lb = (float*)((char*)d_ws + OFF_LB);
  u16* wb = (u16*)((char*)d_ws + OFF_WB);

  if (ws_size >= NEED) {
    init_state<<<1, 1024, 0, stream>>>(h0, c0, hbufs, cbufs);
    const long long n8 = (long long)VOCAB * HIDDEN / 8;
    convert_wlin<<<(int)((n8 + 255) / 256), 256, 0, stream>>>(wlin, wb);
    for (int t = 0; t < SEQLEN; ++t) {
      lstm_step<<<HIDDEN / 4, 256, 0, stream>>>(emb, wih, whh, bih, bhh, seq,
                                                wlin, blin, hbufs, cbufs,
                                                partials, Lb, t);
      if (t < SEQLEN - 1)
        logits_screen<<<NSB, 256, 0, stream>>>(wb, blin, hbufs, Lb, partials, t);
    }
    // final h lives at parity (511+1)&1 == 0
    logits_out<<<(VOCAB + 3) / 4, 256, 0, stream>>>(wlin, blin, hbufs, out);
  } else {
    // fallback: round-0 fp32 path
    u64* p0 = (u64*)d_ws;
    float* hb0 = (float*)((char*)d_ws + 4096);
    float* cb0 = hb0 + 2 * HIDDEN;
    init_state_v0<<<1, 1024, 0, stream>>>(h0, c0, hb0, cb0, p0);
    for (int t = 0; t < SEQLEN; ++t) {
      lstm_step_v0<<<HIDDEN / 4, 256, 0, stream>>>(emb, wih, whh, bih, bhh, seq,
                                                   hb0, cb0, p0, t);
      logits_step_v0<<<(VOCAB + 3) / 4, 256, 0, stream>>>(wlin, blin, hb0, out,
                                                          p0, t);
    }
  }
}

// Round 5
// 22622.331 us; speedup vs baseline: 4.5279x; 1.0221x over previous
//
#include <hip/hip_runtime.h>

#define VOCAB 50257
#define EMBED 512
#define HIDDEN 1024
#define SEQLEN 512
#define XDIM 1024   // 2*EMBED
#define NSB 1571    // ceil(VOCAB/32): screen blocks / per-block max slots
#define CANDB 128   // candidate-block cap
#define CANDR 512   // candidate-row cap

typedef unsigned long long u64;
typedef unsigned int u32;
typedef unsigned short u16;

// monotone mapping float -> u32 (order-preserving for all finite floats)
__device__ __forceinline__ u32 fmono(float f) {
  u32 b = __float_as_uint(f);
  return b ^ ((b & 0x80000000u) ? 0xFFFFFFFFu : 0x80000000u);
}
// inverse of fmono
__device__ __forceinline__ float funmono(u32 v) {
  u32 b = (v & 0x80000000u) ? (v ^ 0x80000000u) : ~v;
  return __uint_as_float(b);
}

__device__ __forceinline__ float wave_reduce_sum(float v) {
#pragma unroll
  for (int off = 32; off > 0; off >>= 1) v += __shfl_down(v, off);
  return v;
}

__device__ __forceinline__ u64 wave_reduce_max_u64(u64 v) {
#pragma unroll
  for (int off = 32; off > 0; off >>= 1) {
    u64 o = __shfl_down(v, off);
    if (o > v) v = o;
  }
  return v;
}

// fp32 -> bf16 round-to-nearest-even (finite inputs only)
__device__ __forceinline__ u16 f2bf_rne(float f) {
  u32 u = __float_as_uint(f);
  u32 r = (u + 0x7FFFu + ((u >> 16) & 1u)) >> 16;
  return (u16)r;
}

// dot of 8 bf16 (packed in uint4) with 8 fp32 (two float4)
__device__ __forceinline__ float dot8(uint4 w, float4 hx, float4 hy) {
  float a = 0.f;
  u32 u;
  u = w.x; a += __uint_as_float(u << 16) * hx.x + __uint_as_float(u & 0xFFFF0000u) * hx.y;
  u = w.y; a += __uint_as_float(u << 16) * hx.z + __uint_as_float(u & 0xFFFF0000u) * hx.w;
  u = w.z; a += __uint_as_float(u << 16) * hy.x + __uint_as_float(u & 0xFFFF0000u) * hy.y;
  u = w.w; a += __uint_as_float(u << 16) * hy.z + __uint_as_float(u & 0xFFFF0000u) * hy.w;
  return a;
}

// ============================ setup kernels ============================

__global__ void init_state(const float* __restrict__ h0, const float* __restrict__ c0,
                           float* __restrict__ hbufs, float* __restrict__ cbufs) {
  int i = threadIdx.x;
  if (i < HIDDEN) {
    hbufs[i] = h0[i];
    cbufs[i] = c0[i];
  }
}

// one-shot fp32 -> bf16 conversion of W_lin into workspace
__global__ __launch_bounds__(256)
void convert_wlin(const float* __restrict__ wlin, u16* __restrict__ wb) {
  const long long i8 = (long long)blockIdx.x * 256 + threadIdx.x;  // group of 8 floats
  const long long n8 = (long long)VOCAB * HIDDEN / 8;
  if (i8 >= n8) return;
  const float4* src = (const float4*)wlin;
  float4 a = src[2 * i8];
  float4 b = src[2 * i8 + 1];
  uint4 o;
  o.x = (u32)f2bf_rne(a.x) | ((u32)f2bf_rne(a.y) << 16);
  o.y = (u32)f2bf_rne(a.z) | ((u32)f2bf_rne(a.w) << 16);
  o.z = (u32)f2bf_rne(b.x) | ((u32)f2bf_rne(b.y) << 16);
  o.w = (u32)f2bf_rne(b.z) | ((u32)f2bf_rne(b.w) << 16);
  ((uint4*)wb)[i8] = o;
}

// ============================ fast path ============================

// LSTM step, 256 blocks x 256 threads. Prologue (t>0, redundant per block):
// statically-unrolled max-fold over NSB per-screen-block maxima (NO arrays ->
// no scratch, rule #20); rigorous bf16 threshold; candidate blocks via a
// reload pass (L2-hot); scan their 32-row Lb segments; exact fp32 recompute
// of candidate rows (round-0 dot order) -> ptok. Then the LSTM gates.
// Cross-kernel visibility via stream order only — no fences, no atomics.
__global__ __launch_bounds__(256)
void lstm_step(const float* __restrict__ emb,
               const float* __restrict__ wih, const float* __restrict__ whh,
               const float* __restrict__ bih, const float* __restrict__ bhh,
               const int* __restrict__ seq,
               const float* __restrict__ wlin, const float* __restrict__ blin,
               float* __restrict__ hbufs, float* __restrict__ cbufs,
               const u64* __restrict__ partials, const float* __restrict__ Lb,
               int t) {
  __shared__ __align__(16) float xs[XDIM];
  __shared__ __align__(16) float hs[HIDDEN];
  __shared__ float sred[4];
  __shared__ u64 mred[4];
  __shared__ u64 bred[4];
  __shared__ int listb[CANDB];
  __shared__ int listr[CANDR];
  __shared__ int cntb, cntr;
  __shared__ int ptokS;

  const int tid = threadIdx.x;
  const int lane = tid & 63;
  const int wid = tid >> 6;

  const float* hin = hbufs + (t & 1) * HIDDEN;
  const float* cin = cbufs + (t & 1) * HIDDEN;
  float* hout = hbufs + ((t + 1) & 1) * HIDDEN;
  float* cout = cbufs + ((t + 1) & 1) * HIDDEN;

  const u64* part = partials + (((t + 1) & 1)) * NSB;  // parity (t-1)&1

  // pass 1: global max of screen-block maxima (static unroll -> pure regs)
  u64 v = 0;
  if (t > 0) {
#pragma unroll
    for (int k = 0; k < 7; ++k) {
      const int i = tid + (k << 8);
      if (i < NSB) {
        const u64 p = part[i];
        if (p > v) v = p;
      }
    }
  }

  // stage h; fold |h| sum in the same pass (registers, no LDS round-trip)
  float s = 0.f;
  for (int i = tid; i < HIDDEN; i += 256) {
    const float hv = hin[i];
    hs[i] = hv;
    s += fabsf(hv);
  }

  int ptok = 0;
  if (t > 0) {
    v = wave_reduce_max_u64(v);
    s = wave_reduce_sum(s);
    if (lane == 0) {
      mred[wid] = v;
      sred[wid] = s;
    }
    if (tid == 0) { cntb = 0; cntr = 0; }
    __syncthreads();

    u64 m = mred[0];
    if (mred[1] > m) m = mred[1];
    if (mred[2] > m) m = mred[2];
    if (mred[3] > m) m = mred[3];
    const float S = sred[0] + sred[1] + sred[2] + sred[3];
    const float maxb = funmono((u32)(m >> 32));
    // |L_bf16 - L_fp32| <= S*(1/32)*2^-9 per side (RNE), + fp32-order margin
    const float thr = maxb - 2.0f * (S * 6.1035156e-5f) - 2e-3f;

    // pass 2: candidate blocks (reload; L2-hot after pass 1)
#pragma unroll
    for (int k = 0; k < 7; ++k) {
      const int i = tid + (k << 8);
      if (i < NSB && funmono((u32)(part[i] >> 32)) >= thr) {
        int ix = atomicAdd(&cntb, 1);
        if (ix < CANDB) listb[ix] = i;
      }
    }
    __syncthreads();
    const int nb = (cntb < CANDB) ? cntb : CANDB;

    // scan candidate blocks' Lb segments for candidate rows
    for (int idx = tid; idx < nb * 32; idx += 256) {
      const int row = listb[idx >> 5] * 32 + (idx & 31);
      if (row < VOCAB && Lb[row] >= thr) {
        int ix = atomicAdd(&cntr, 1);
        if (ix < CANDR) listr[ix] = row;
      }
    }
    __syncthreads();
    const int nr = (cntr < CANDR) ? cntr : CANDR;

    // exact fp32 recompute of candidate rows, one wave per row
    u64 best = 0;
    for (int ci = wid; ci < nr; ci += 4) {
      const int row = listr[ci];
      const float4* wr = (const float4*)(wlin + (size_t)row * HIDDEN);
      float a = 0.f;
#pragma unroll
      for (int i = 0; i < 4; ++i) {
        const int k = lane + i * 64;
        const float4 w4 = wr[k];
        const float4 h4 = *((const float4*)&hs[k * 4]);
        a += w4.x * h4.x + w4.y * h4.y + w4.z * h4.z + w4.w * h4.w;
      }
      a = wave_reduce_sum(a);
      if (lane == 0) {
        const u64 pk = ((u64)fmono(a + blin[row]) << 32) | (u32)(VOCAB - row);
        if (pk > best) best = pk;
      }
    }
    if (lane == 0) bred[wid] = best;
    __syncthreads();
    if (tid == 0) {
      u64 b = bred[0];
      if (bred[1] > b) b = bred[1];
      if (bred[2] > b) b = bred[2];
      if (bred[3] > b) b = bred[3];
      ptokS = VOCAB - (int)(u32)(b & 0xFFFFFFFFu);
    }
    __syncthreads();
    ptok = ptokS;
  }

  // stage x = [prev_embed, tok_embed]
  const int tok = seq[t];
  for (int i = tid; i < EMBED; i += 256) {
    xs[i] = (t == 0) ? 0.0f : emb[(size_t)ptok * EMBED + i];
    xs[EMBED + i] = emb[(size_t)tok * EMBED + i];
  }
  __syncthreads();  // covers hs writes too (t==0 path)

  // gates: each wave computes rows {j, j+H, j+2H, j+3H}
  const int j = blockIdx.x * 4 + wid;
  float acc[4];
#pragma unroll
  for (int g = 0; g < 4; ++g) {
    const float4* wx = (const float4*)(wih + (size_t)(g * HIDDEN + j) * XDIM);
    const float4* wh = (const float4*)(whh + (size_t)(g * HIDDEN + j) * HIDDEN);
    float a = 0.f;
#pragma unroll
    for (int i = 0; i < 4; ++i) {
      const int k = lane + i * 64;
      float4 w4 = wx[k];
      float4 x4 = *((const float4*)&xs[k * 4]);
      a += w4.x * x4.x + w4.y * x4.y + w4.z * x4.z + w4.w * x4.w;
      float4 v4 = wh[k];
      float4 h4 = *((const float4*)&hs[k * 4]);
      a += v4.x * h4.x + v4.y * h4.y + v4.z * h4.z + v4.w * h4.w;
    }
    acc[g] = wave_reduce_sum(a);
  }

  if (lane == 0) {
    float gi = acc[0] + bih[j] + bhh[j];
    float gf = acc[1] + bih[HIDDEN + j] + bhh[HIDDEN + j];
    float gg = acc[2] + bih[2 * HIDDEN + j] + bhh[2 * HIDDEN + j];
    float go = acc[3] + bih[3 * HIDDEN + j] + bhh[3 * HIDDEN + j];
    float si = 1.0f / (1.0f + expf(-gi));
    float sf = 1.0f / (1.0f + expf(-gf));
    float tg = tanhf(gg);
    float so = 1.0f / (1.0f + expf(-go));
    float c2 = sf * cin[j] + si * tg;
    float h2 = so * tanhf(c2);
    cout[j] = c2;
    hout[j] = h2;
  }
}

// bf16 screen: Lb = W_bf16 @ h + b for its 32 rows; per-block packed max
// written to the block's OWN slot (plain store — no atomics, no fences).
__global__ __launch_bounds__(256)
void logits_screen(const u16* __restrict__ wb, const float* __restrict__ blin,
                   const float* __restrict__ hbufs, float* __restrict__ Lb,
                   u64* __restrict__ partials, int t) {
  __shared__ u64 red[4];
  const int tid = threadIdx.x;
  const int lane = tid & 63;
  const int wid = tid >> 6;

  const float* h = hbufs + ((t + 1) & 1) * HIDDEN;

  // h fragments in registers (no LDS bank conflicts in the hot loop)
  const float4* h4p = (const float4*)h;
  const float4 ha0 = h4p[2 * lane];
  const float4 ha1 = h4p[2 * lane + 1];
  const float4 hb0 = h4p[2 * (lane + 64)];
  const float4 hb1 = h4p[2 * (lane + 64) + 1];

  const int row0 = blockIdx.x * 32 + wid * 8;
  float acc[8];
  uint4 w0[4], w1[4];
  const uint4 z4 = make_uint4(0u, 0u, 0u, 0u);

  // group 0: rows 0..3 — stage all loads, then compute (ILP)
#pragma unroll
  for (int r = 0; r < 4; ++r) {
    const int row = row0 + r;
    const uint4* wr = (const uint4*)(wb + (size_t)row * HIDDEN);
    const bool ok = row < VOCAB;
    w0[r] = ok ? wr[lane] : z4;
    w1[r] = ok ? wr[lane + 64] : z4;
  }
#pragma unroll
  for (int r = 0; r < 4; ++r)
    acc[r] = dot8(w0[r], ha0, ha1) + dot8(w1[r], hb0, hb1);

  // group 1: rows 4..7
#pragma unroll
  for (int r = 0; r < 4; ++r) {
    const int row = row0 + 4 + r;
    const uint4* wr = (const uint4*)(wb + (size_t)row * HIDDEN);
    const bool ok = row < VOCAB;
    w0[r] = ok ? wr[lane] : z4;
    w1[r] = ok ? wr[lane + 64] : z4;
  }
#pragma unroll
  for (int r = 0; r < 4; ++r)
    acc[4 + r] = dot8(w0[r], ha0, ha1) + dot8(w1[r], hb0, hb1);

  // 8 interleaved reduce chains
#pragma unroll
  for (int off = 32; off > 0; off >>= 1) {
#pragma unroll
    for (int r = 0; r < 8; ++r) acc[r] += __shfl_down(acc[r], off);
  }

  u64 best = 0;
  if (lane == 0) {
#pragma unroll
    for (int r = 0; r < 8; ++r) {
      const int row = row0 + r;
      if (row < VOCAB) {
        const float lg = acc[r] + blin[row];
        Lb[row] = lg;
        const u64 pk = ((u64)fmono(lg) << 32) | (u32)(VOCAB - row);
        if (pk > best) best = pk;
      }
    }
    red[wid] = best;
  }
  __syncthreads();
  if (tid == 0) {
    u64 m = red[0];
    if (red[1] > m) m = red[1];
    if (red[2] > m) m = red[2];
    if (red[3] > m) m = red[3];
    partials[(t & 1) * NSB + blockIdx.x] = m;  // own slot, plain store
  }
}

// exact fp32 logits of the final step -> d_out (identical dot to round 0)
__global__ __launch_bounds__(256)
void logits_out(const float* __restrict__ wlin, const float* __restrict__ blin,
                const float* __restrict__ h, float* __restrict__ out) {
  __shared__ __align__(16) float hs[HIDDEN];
  const int tid = threadIdx.x;
  const int lane = tid & 63;
  const int wid = tid >> 6;
  for (int i = tid; i < HIDDEN; i += 256) hs[i] = h[i];
  __syncthreads();
  const int row = blockIdx.x * 4 + wid;
  if (row < VOCAB) {
    const float4* wr = (const float4*)(wlin + (size_t)row * HIDDEN);
    float a = 0.f;
#pragma unroll
    for (int i = 0; i < 4; ++i) {
      const int k = lane + i * 64;
      float4 w4 = wr[k];
      float4 h4 = *((const float4*)&hs[k * 4]);
      a += w4.x * h4.x + w4.y * h4.y + w4.z * h4.z + w4.w * h4.w;
    }
    a = wave_reduce_sum(a);
    if (lane == 0) out[row] = a + blin[row];
  }
}

// ====================== fallback (round-0) path ======================

__global__ void init_state_v0(const float* __restrict__ h0, const float* __restrict__ c0,
                              float* __restrict__ hbufs, float* __restrict__ cbufs,
                              u64* __restrict__ partials) {
  int i = threadIdx.x;
  if (i < HIDDEN) {
    hbufs[i] = h0[i];
    cbufs[i] = c0[i];
  }
  if (i < 512) partials[i] = 0ull;
}

__global__ __launch_bounds__(256)
void lstm_step_v0(const float* __restrict__ emb,
                  const float* __restrict__ wih, const float* __restrict__ whh,
                  const float* __restrict__ bih, const float* __restrict__ bhh,
                  const int* __restrict__ seq,
                  float* __restrict__ hbufs, float* __restrict__ cbufs,
                  u64* __restrict__ partials, int t) {
  __shared__ __align__(16) float xs[XDIM];
  __shared__ __align__(16) float hs[HIDDEN];
  __shared__ u64 red[4];
  __shared__ int ptok_s;

  const int tid = threadIdx.x;
  const int lane = tid & 63;
  const int wid = tid >> 6;

  const float* hin = hbufs + (t & 1) * HIDDEN;
  const float* cin = cbufs + (t & 1) * HIDDEN;
  float* hout = hbufs + ((t + 1) & 1) * HIDDEN;
  float* cout = cbufs + ((t + 1) & 1) * HIDDEN;

  int ptok = -1;
  if (t > 0) {
    const u64* part = partials + ((t + 1) & 1) * 256;
    u64 v = wave_reduce_max_u64(part[tid]);
    if (lane == 0) red[wid] = v;
    __syncthreads();
    if (tid == 0) {
      u64 m = red[0];
      if (red[1] > m) m = red[1];
      if (red[2] > m) m = red[2];
      if (red[3] > m) m = red[3];
      ptok_s = VOCAB - (int)(u32)(m & 0xFFFFFFFFu);
    }
    __syncthreads();
    ptok = ptok_s;
  }
  if (blockIdx.x == 0) partials[(t & 1) * 256 + tid] = 0ull;

  const int tok = seq[t];
  for (int i = tid; i < EMBED; i += 256) {
    xs[i] = (t == 0) ? 0.0f : emb[(size_t)ptok * EMBED + i];
    xs[EMBED + i] = emb[(size_t)tok * EMBED + i];
  }
  for (int i = tid; i < HIDDEN; i += 256) hs[i] = hin[i];
  __syncthreads();

  const int j = blockIdx.x * 4 + wid;
  float acc[4];
#pragma unroll
  for (int g = 0; g < 4; ++g) {
    const float4* wx = (const float4*)(wih + (size_t)(g * HIDDEN + j) * XDIM);
    const float4* wh = (const float4*)(whh + (size_t)(g * HIDDEN + j) * HIDDEN);
    float a = 0.f;
#pragma unroll
    for (int i = 0; i < 4; ++i) {
      const int k = lane + i * 64;
      float4 w4 = wx[k];
      float4 x4 = *((const float4*)&xs[k * 4]);
      a += w4.x * x4.x + w4.y * x4.y + w4.z * x4.z + w4.w * x4.w;
      float4 v4 = wh[k];
      float4 h4 = *((const float4*)&hs[k * 4]);
      a += v4.x * h4.x + v4.y * h4.y + v4.z * h4.z + v4.w * h4.w;
    }
    acc[g] = wave_reduce_sum(a);
  }

  if (lane == 0) {
    float gi = acc[0] + bih[j] + bhh[j];
    float gf = acc[1] + bih[HIDDEN + j] + bhh[HIDDEN + j];
    float gg = acc[2] + bih[2 * HIDDEN + j] + bhh[2 * HIDDEN + j];
    float go = acc[3] + bih[3 * HIDDEN + j] + bhh[3 * HIDDEN + j];
    float si = 1.0f / (1.0f + expf(-gi));
    float sf = 1.0f / (1.0f + expf(-gf));
    float tg = tanhf(gg);
    float so = 1.0f / (1.0f + expf(-go));
    float c2 = sf * cin[j] + si * tg;
    float h2 = so * tanhf(c2);
    cout[j] = c2;
    hout[j] = h2;
  }
}

__global__ __launch_bounds__(256)
void logits_step_v0(const float* __restrict__ wlin, const float* __restrict__ blin,
                    const float* __restrict__ hbufs, float* __restrict__ out,
                    u64* __restrict__ partials, int t) {
  __shared__ __align__(16) float hs[HIDDEN];
  __shared__ u64 red[4];
  const int tid = threadIdx.x;
  const int lane = tid & 63;
  const int wid = tid >> 6;

  const float* h = hbufs + ((t + 1) & 1) * HIDDEN;
  for (int i = tid; i < HIDDEN; i += 256) hs[i] = h[i];
  __syncthreads();

  const int row = blockIdx.x * 4 + wid;
  u64 pk = 0ull;
  if (row < VOCAB) {
    const float4* wr = (const float4*)(wlin + (size_t)row * HIDDEN);
    float a = 0.f;
#pragma unroll
    for (int i = 0; i < 4; ++i) {
      const int k = lane + i * 64;
      float4 w4 = wr[k];
      float4 h4 = *((const float4*)&hs[k * 4]);
      a += w4.x * h4.x + w4.y * h4.y + w4.z * h4.z + w4.w * h4.w;
    }
    a = wave_reduce_sum(a);
    if (lane == 0) {
      float logit = a + blin[row];
      out[row] = logit;
      pk = ((u64)fmono(logit) << 32) | (u32)(VOCAB - row);
    }
  }
  if (lane == 0) red[wid] = pk;
  __syncthreads();
  if (tid == 0) {
    u64 m = red[0];
    if (red[1] > m) m = red[1];
    if (red[2] > m) m = red[2];
    if (red[3] > m) m = red[3];
    atomicMax(&partials[(t & 1) * 256 + (blockIdx.x & 255)], m);
  }
}

extern "C" void kernel_launch(void* const* d_in, const int* in_sizes, int n_in,
                              void* d_out, int out_size, void* d_ws, size_t ws_size,
                              hipStream_t stream) {
  const int* seq = (const int*)d_in[0];
  const float* h0 = (const float*)d_in[1];
  const float* c0 = (const float*)d_in[2];
  const float* emb = (const float*)d_in[3];
  const float* wih = (const float*)d_in[4];
  const float* whh = (const float*)d_in[5];
  const float* bih = (const float*)d_in[6];
  const float* bhh = (const float*)d_in[7];
  const float* wlin = (const float*)d_in[8];
  const float* blin = (const float*)d_in[9];
  float* out = (float*)d_out;

  // ws layout (aligned offsets)
  const size_t OFF_P = 0;                          // partials: 2*NSB u64
  const size_t OFF_H = 25600;                      // hbufs: 2*1024 f
  const size_t OFF_C = OFF_H + 8192;               // cbufs: 2*1024 f
  const size_t OFF_LB = OFF_C + 8192;              // Lb: VOCAB f (pad to 16)
  const size_t OFF_WB = OFF_LB + 201216;           // wb: VOCAB*HIDDEN bf16
  const size_t NEED = OFF_WB + (size_t)VOCAB * HIDDEN * 2;

  u64* partials = (u64*)((char*)d_ws + OFF_P);
  float* hbufs = (float*)((char*)d_ws + OFF_H);
  float* cbufs = (float*)((char*)d_ws + OFF_C);
  float* Lb = (float*)((char*)d_ws + OFF_LB);
  u16* wb = (u16*)((char*)d_ws + OFF_WB);

  if (ws_size >= NEED) {
    init_state<<<1, 1024, 0, stream>>>(h0, c0, hbufs, cbufs);
    const long long n8 = (long long)VOCAB * HIDDEN / 8;
    convert_wlin<<<(int)((n8 + 255) / 256), 256, 0, stream>>>(wlin, wb);
    for (int t = 0; t < SEQLEN; ++t) {
      lstm_step<<<HIDDEN / 4, 256, 0, stream>>>(emb, wih, whh, bih, bhh, seq,
                                                wlin, blin, hbufs, cbufs,
                                                partials, Lb, t);
      if (t < SEQLEN - 1)
        logits_screen<<<NSB, 256, 0, stream>>>(wb, blin, hbufs, Lb, partials, t);
    }
    // final h lives at parity (511+1)&1 == 0
    logits_out<<<(VOCAB + 3) / 4, 256, 0, stream>>>(wlin, blin, hbufs, out);
  } else {
    // fallback: round-0 fp32 path
    u64* p0 = (u64*)d_ws;
    float* hb0 = (float*)((char*)d_ws + 4096);
    float* cb0 = hb0 + 2 * HIDDEN;
    init_state_v0<<<1, 1024, 0, stream>>>(h0, c0, hb0, cb0, p0);
    for (int t = 0; t < SEQLEN; ++t) {
      lstm_step_v0<<<HIDDEN / 4, 256, 0, stream>>>(emb, wih, whh, bih, bhh, seq,
                                                   hb0, cb0, p0, t);
      logits_step_v0<<<(VOCAB + 3) / 4, 256, 0, stream>>>(wlin, blin, hb0, out,
                                                          p0, t);
    }
  }
}